// Round 2
// baseline (9836.994 us; speedup 1.0000x reference)
//
#include <hip/hip_runtime.h>
#include <hip/hip_bf16.h>

typedef __hip_bfloat16 bf16;
typedef __attribute__((ext_vector_type(8))) short short8;
typedef __attribute__((ext_vector_type(4))) float float4v;

#define B_    1024
#define H_    512
#define G4H   2048
#define F_    32
#define CIN_  4
#define K_    30
#define STRIDE_ 6
#define L_    924
#define T_    150
#define KD_   40
#define NSTEPS_ 10

__device__ __forceinline__ float sigmoidf_(float x) { return 1.f / (1.f + __expf(-x)); }
__device__ __forceinline__ float tanhf_(float x)    { return 1.f - 2.f / (__expf(2.f * x) + 1.f); }

// ---------------------------------------------------------------------------
// fp32 -> bf16 weight conversion
// ---------------------------------------------------------------------------
__global__ __launch_bounds__(256) void cvt_kernel(const float* __restrict__ src,
                                                  bf16* __restrict__ dst, int n) {
    int i = blockIdx.x * 256 + threadIdx.x;
    if (i < n) dst[i] = __float2bfloat16(src[i]);
}

// ---------------------------------------------------------------------------
// bias precompute: b0 = bih0+bhh0, b1 = bih1+bhh1 (fp32)
// ---------------------------------------------------------------------------
__global__ void bias_kernel(const float* __restrict__ bih0, const float* __restrict__ bhh0,
                            const float* __restrict__ bih1, const float* __restrict__ bhh1,
                            float* __restrict__ b0, float* __restrict__ b1) {
    int i = blockIdx.x * 256 + threadIdx.x;
    if (i < G4H)      b0[i] = bih0[i] + bhh0[i];
    else if (i < 2*G4H) { int j = i - G4H; b1[j] = bih1[j] + bhh1[j]; }
}

// ---------------------------------------------------------------------------
// encoder conv1d + relu -> seq [T, B, F] bf16
// one block per batch row b; w and x[b] staged in LDS as fp32
// ---------------------------------------------------------------------------
__global__ __launch_bounds__(256) void conv_kernel(
    const float* __restrict__ x,    // [B, 4, 924] fp32
    const float* __restrict__ w,    // [32, 4, 30] fp32
    const float* __restrict__ cb,   // [32] fp32
    bf16* __restrict__ seq)         // [150, 1024, 32] bf16
{
    __shared__ float w_lds[CIN_ * K_ * F_];   // [r=c*30+k][f] transposed
    __shared__ float x_lds[CIN_ * L_];
    int tid = threadIdx.x;
    int b = blockIdx.x;
    for (int i = tid; i < CIN_ * K_ * F_; i += 256) {
        int f = i & 31, r = i >> 5;
        w_lds[r * 32 + f] = w[f * (CIN_ * K_) + r];
    }
    const float* xb = x + (size_t)b * (CIN_ * L_);
    for (int i = tid; i < CIN_ * L_; i += 256)
        x_lds[i] = xb[i];
    __syncthreads();
    int f = tid & 31, tt = tid >> 5;          // tt in 0..7
    float cbf = cb[f];
    for (int t0 = 0; t0 < T_; t0 += 8) {
        int t = t0 + tt;
        if (t < T_) {
            float acc = cbf;
            #pragma unroll
            for (int c = 0; c < CIN_; ++c) {
                const float* xr = x_lds + c * L_ + t * STRIDE_;
                const float* wr = w_lds + c * K_ * 32 + f;
                #pragma unroll
                for (int k = 0; k < K_; ++k)
                    acc += xr[k] * wr[k * 32];
            }
            acc = fmaxf(acc, 0.f);
            seq[(size_t)t * (B_ * F_) + b * F_ + f] = __float2bfloat16(acc);
        }
    }
}

// ---------------------------------------------------------------------------
// one LSTM layer step: G = X@Wih^T + H@Whh^T + b ; gate pointwise; update c,h
// grid (64, 32): blockIdx.x = m-tile (16 rows of B), blockIdx.y = j-tile (16 of 512)
// each 1-wave block computes 16x16 C tile for each of the 4 gates
// ---------------------------------------------------------------------------
__global__ __launch_bounds__(64) void lstm_step(
    const bf16* __restrict__ X, int kx,       // [B, kx] bf16
    const bf16* __restrict__ Wih,             // [2048, kx] bf16
    const bf16* __restrict__ Hin,             // [B, 512] bf16
    const bf16* __restrict__ Whh,             // [2048, 512] bf16
    const float* __restrict__ bias,           // [2048] fp32
    float* __restrict__ Cst,                  // [B, 512] fp32 in/out
    bf16* __restrict__ Hout)                  // [B, 512] bf16
{
    const int lane = threadIdx.x;
    const int m0 = blockIdx.x * 16;
    const int j0 = blockIdx.y * 16;
    const int row = lane & 15;
    const int quad = lane >> 4;

    float4v zero = {0.f, 0.f, 0.f, 0.f};
    float4v acc[4] = {zero, zero, zero, zero};

    // X @ Wih^T
    {
        const bf16* xrow = X + (size_t)(m0 + row) * kx + quad * 8;
        for (int kb = 0; kb < kx; kb += 32) {
            short8 a = *(const short8*)(xrow + kb);
            #pragma unroll
            for (int g = 0; g < 4; ++g) {
                const bf16* wrow = Wih + (size_t)(g * H_ + j0 + row) * kx + kb + quad * 8;
                short8 bb = *(const short8*)(wrow);
                acc[g] = __builtin_amdgcn_mfma_f32_16x16x32_bf16(a, bb, acc[g], 0, 0, 0);
            }
        }
    }
    // H @ Whh^T
    {
        const bf16* hrow = Hin + (size_t)(m0 + row) * H_ + quad * 8;
        for (int kb = 0; kb < H_; kb += 32) {
            short8 a = *(const short8*)(hrow + kb);
            #pragma unroll
            for (int g = 0; g < 4; ++g) {
                const bf16* wrow = Whh + (size_t)(g * H_ + j0 + row) * H_ + kb + quad * 8;
                short8 bb = *(const short8*)(wrow);
                acc[g] = __builtin_amdgcn_mfma_f32_16x16x32_bf16(a, bb, acc[g], 0, 0, 0);
            }
        }
    }
    // epilogue: gates i,f,g,o ; c' = sig(f)*c + sig(i)*tanh(g) ; h' = sig(o)*tanh(c')
    const int j = j0 + row;                   // C/D: col = lane&15
    const float bi = bias[j];
    const float bf_v = bias[H_ + j];
    const float bg = bias[2 * H_ + j];
    const float bo = bias[3 * H_ + j];
    #pragma unroll
    for (int r = 0; r < 4; ++r) {
        const int brow = m0 + quad * 4 + r;   // C/D: row = quad*4 + reg
        float ig = sigmoidf_(acc[0][r] + bi);
        float fg = sigmoidf_(acc[1][r] + bf_v);
        float gg = tanhf_(acc[2][r] + bg);
        float og = sigmoidf_(acc[3][r] + bo);
        size_t idx = (size_t)brow * H_ + j;
        float cn = fg * Cst[idx] + ig * gg;
        Cst[idx] = cn;
        Hout[idx] = __float2bfloat16(og * tanhf_(cn));
    }
}

// ---------------------------------------------------------------------------
// y = h1 @ dec_w^T + dec_b  -> Y bf16 [B,32]; optionally store fut fp32
// ---------------------------------------------------------------------------
__global__ __launch_bounds__(256) void dec_kernel(
    const bf16* __restrict__ Hb,       // [B, 512] bf16
    const float* __restrict__ dec_w,   // [32, 512] fp32
    const float* __restrict__ dec_b,   // [32] fp32
    bf16* __restrict__ Y,              // [B, 32] bf16
    float* __restrict__ fut, int step) // [B, 32, 10] fp32
{
    int tid = blockIdx.x * 256 + threadIdx.x;  // 32768
    int b = tid >> 5, f = tid & 31;
    const bf16*  h = Hb + (size_t)b * H_;
    const float* w = dec_w + f * H_;
    float acc = dec_b[f];
    for (int jj = 0; jj < H_; ++jj)
        acc += __bfloat162float(h[jj]) * w[jj];
    Y[tid] = __float2bfloat16(acc);
    if (step >= 0) fut[(size_t)b * (F_ * NSTEPS_) + f * NSTEPS_ + step] = acc;
}

// ---------------------------------------------------------------------------
// ConvTranspose1d: out[b][jj] = sum_f sum_t fut[b][f][t] * dw[f][jj-t], jj<49
// ---------------------------------------------------------------------------
__global__ __launch_bounds__(256) void deconv_kernel(
    const float* __restrict__ fut,    // [B, 32, 10] fp32
    const float* __restrict__ dw,     // [32, 1, 40] fp32
    float* __restrict__ out)          // [B, 1, 49] fp32
{
    int idx = blockIdx.x * 256 + threadIdx.x;
    if (idx >= B_ * 49) return;
    int b = idx / 49, jj = idx % 49;
    int tlo = jj - (KD_ - 1); if (tlo < 0) tlo = 0;
    int thi = jj; if (thi > NSTEPS_ - 1) thi = NSTEPS_ - 1;
    float acc = 0.f;
    for (int f = 0; f < F_; ++f) {
        const float* fr = fut + (size_t)b * (F_ * NSTEPS_) + f * NSTEPS_;
        const float* wr = dw + f * KD_;
        for (int t = tlo; t <= thi; ++t)
            acc += fr[t] * wr[jj - t];
    }
    out[idx] = acc;
}

// ---------------------------------------------------------------------------
extern "C" void kernel_launch(void* const* d_in, const int* in_sizes, int n_in,
                              void* d_out, int out_size, void* d_ws, size_t ws_size,
                              hipStream_t stream) {
    const float* x       = (const float*)d_in[0];
    const float* conv_w  = (const float*)d_in[1];
    const float* conv_b  = (const float*)d_in[2];
    const float* Wih0f   = (const float*)d_in[3];
    const float* Whh0f   = (const float*)d_in[4];
    const float* bih0    = (const float*)d_in[5];
    const float* bhh0    = (const float*)d_in[6];
    const float* Wih1f   = (const float*)d_in[7];
    const float* Whh1f   = (const float*)d_in[8];
    const float* bih1    = (const float*)d_in[9];
    const float* bhh1    = (const float*)d_in[10];
    const float* dec_w   = (const float*)d_in[11];
    const float* dec_b   = (const float*)d_in[12];
    const float* deconvw = (const float*)d_in[13];
    float* out = (float*)d_out;

    // workspace carve-up (256B aligned)
    char* ws = (char*)d_ws;
    size_t off = 0;
    auto alloc = [&](size_t bytes) { char* p = ws + off; off = (off + bytes + 255) & ~(size_t)255; return p; };
    bf16*  seq   = (bf16*) alloc((size_t)T_ * B_ * F_ * 2);
    float* b0    = (float*)alloc(G4H * 4);
    float* b1    = (float*)alloc(G4H * 4);
    float* c0    = (float*)alloc((size_t)B_ * H_ * 4);
    float* c1    = (float*)alloc((size_t)B_ * H_ * 4);
    bf16*  h0[2], *h1[2];
    h0[0] = (bf16*)alloc((size_t)B_ * H_ * 2);
    h0[1] = (bf16*)alloc((size_t)B_ * H_ * 2);
    h1[0] = (bf16*)alloc((size_t)B_ * H_ * 2);
    h1[1] = (bf16*)alloc((size_t)B_ * H_ * 2);
    bf16*  y     = (bf16*) alloc((size_t)B_ * F_ * 2);
    float* fut   = (float*)alloc((size_t)B_ * F_ * NSTEPS_ * 4);
    bf16*  Wih0b = (bf16*) alloc((size_t)G4H * F_ * 2);
    bf16*  Whh0b = (bf16*) alloc((size_t)G4H * H_ * 2);
    bf16*  Wih1b = (bf16*) alloc((size_t)G4H * H_ * 2);
    bf16*  Whh1b = (bf16*) alloc((size_t)G4H * H_ * 2);

    // zero initial states
    hipMemsetAsync(c0, 0, (size_t)B_ * H_ * 4, stream);
    hipMemsetAsync(c1, 0, (size_t)B_ * H_ * 4, stream);
    hipMemsetAsync(h0[0], 0, (size_t)B_ * H_ * 2, stream);
    hipMemsetAsync(h1[0], 0, (size_t)B_ * H_ * 2, stream);

    // weight conversion fp32 -> bf16
    cvt_kernel<<<(G4H * F_ + 255) / 256, 256, 0, stream>>>(Wih0f, Wih0b, G4H * F_);
    cvt_kernel<<<(G4H * H_ + 255) / 256, 256, 0, stream>>>(Whh0f, Whh0b, G4H * H_);
    cvt_kernel<<<(G4H * H_ + 255) / 256, 256, 0, stream>>>(Wih1f, Wih1b, G4H * H_);
    cvt_kernel<<<(G4H * H_ + 255) / 256, 256, 0, stream>>>(Whh1f, Whh1b, G4H * H_);

    bias_kernel<<<16, 256, 0, stream>>>(bih0, bhh0, bih1, bhh1, b0, b1);
    conv_kernel<<<B_, 256, 0, stream>>>(x, conv_w, conv_b, seq);

    dim3 sgrid(64, 32);
    int p0 = 0, p1 = 0;
    for (int t = 0; t < T_; ++t) {
        lstm_step<<<sgrid, 64, 0, stream>>>(seq + (size_t)t * B_ * F_, F_, Wih0b,
                                            h0[p0], Whh0b, b0, c0, h0[1 - p0]);
        p0 ^= 1;
        lstm_step<<<sgrid, 64, 0, stream>>>(h0[p0], H_, Wih1b,
                                            h1[p1], Whh1b, b1, c1, h1[1 - p1]);
        p1 ^= 1;
    }
    dec_kernel<<<128, 256, 0, stream>>>(h1[p1], dec_w, dec_b, y, fut, -1);
    for (int s = 0; s < NSTEPS_; ++s) {
        lstm_step<<<sgrid, 64, 0, stream>>>(y, F_, Wih0b, h0[p0], Whh0b, b0, c0, h0[1 - p0]);
        p0 ^= 1;
        lstm_step<<<sgrid, 64, 0, stream>>>(h0[p0], H_, Wih1b, h1[p1], Whh1b, b1, c1, h1[1 - p1]);
        p1 ^= 1;
        dec_kernel<<<128, 256, 0, stream>>>(h1[p1], dec_w, dec_b, y, fut, s);
    }
    deconv_kernel<<<196, 256, 0, stream>>>(fut, deconvw, out);
}